// Round 2
// baseline (1578.318 us; speedup 1.0000x reference)
//
#include <hip/hip_runtime.h>
#include <hip/hip_bf16.h>
#include <stdint.h>

// Problem constants (from reference)
#define NN 50000          // nodes
#define NE 800000         // edges
#define NR 12             // relations
#define NH 128            // hidden
#define NF 1582           // feature dim

typedef __attribute__((ext_vector_type(8))) short short8;     // 8 x bf16 (4 VGPRs)
typedef __attribute__((ext_vector_type(4))) float floatx4;    // MFMA accumulator

__device__ __forceinline__ float bf2f(unsigned short u) {
    union { unsigned int i; float f; } w; w.i = ((unsigned int)u) << 16; return w.f;
}
__device__ __forceinline__ unsigned short f2bf(float f) {
    union { float f; unsigned int i; } w; w.f = f;
    unsigned int i = w.i;
    return (unsigned short)((i + 0x7FFFu + ((i >> 16) & 1u)) >> 16);  // RNE
}
__device__ __forceinline__ float leaky_f(float v) { return v > 0.f ? v : 0.01f * v; }

// Generic MFMA GEMM: C[M,N] = act(A[M,K] @ B[K,N] + bias)
// A: fp32 (AF32=true, 8B-aligned rows) or bf16 (16B-aligned rows), row stride lda.
// B: bf16 row-major [K, ldb] (pre-converted weights). bias: fp32.
// Each wave: SUB row-tiles of 16 x one 32-col pair. Grid: (ceil(RG/4), N/32).
template<int SUB, bool AF32, bool OUTF32, bool HASBIAS, bool DOLEAKY>
__global__ __launch_bounds__(256) void gemm_k(
    const void* __restrict__ Av, int lda,
    const unsigned short* __restrict__ B, int ldb,
    const float* __restrict__ bias,
    void* __restrict__ Cv, int ldc,
    int Mtiles, int K)
{
    const int wave = threadIdx.x >> 6;
    const int lane = threadIdx.x & 63;
    const int q = lane >> 4;        // quad 0..3
    const int cl = lane & 15;       // row (A) / col (B,C) within tile
    const int RG = (Mtiles + SUB - 1) / SUB;
    const int rg = blockIdx.x * 4 + wave;
    if (rg >= RG) return;
    const int c0 = blockIdx.y * 32;

    floatx4 acc[SUB][2];
#pragma unroll
    for (int s = 0; s < SUB; s++) {
        floatx4 z = {0.f, 0.f, 0.f, 0.f};
        acc[s][0] = z; acc[s][1] = z;
    }

    const int KS = (K + 31) >> 5;
    for (int ks = 0; ks < KS; ks++) {
        const int kb = (ks << 5) + (q << 3);
        union { short8 v; unsigned short u[8]; } b0, b1;
        if (kb + 7 < K) {
#pragma unroll
            for (int j = 0; j < 8; j++) {
                b0.u[j] = B[(size_t)(kb + j) * ldb + c0 + cl];
                b1.u[j] = B[(size_t)(kb + j) * ldb + c0 + 16 + cl];
            }
        } else {
#pragma unroll
            for (int j = 0; j < 8; j++) {
                const bool ok = (kb + j) < K;
                b0.u[j] = ok ? B[(size_t)(kb + j) * ldb + c0 + cl] : 0;
                b1.u[j] = ok ? B[(size_t)(kb + j) * ldb + c0 + 16 + cl] : 0;
            }
        }
#pragma unroll
        for (int s = 0; s < SUB; s++) {
            const int tile = rg * SUB + s;
            if (tile >= Mtiles) break;
            const int row = (tile << 4) + cl;
            union { short8 v; unsigned short u[8]; } a;
            if (AF32) {
                const float* ap = (const float*)Av + (size_t)row * lda + kb;
                if (kb + 7 < K) {
#pragma unroll
                    for (int j = 0; j < 4; j++) {
                        // slice offsets & lda are even => 8B-aligned
                        const float2 t = *(const float2*)__builtin_assume_aligned(ap + 2 * j, 8);
                        a.u[2 * j]     = f2bf(t.x);
                        a.u[2 * j + 1] = f2bf(t.y);
                    }
                } else {
#pragma unroll
                    for (int j = 0; j < 8; j++)
                        a.u[j] = ((kb + j) < K) ? f2bf(ap[j]) : 0;
                }
            } else {
                const unsigned short* ap = (const unsigned short*)Av + (size_t)row * lda + kb;
                if (kb + 7 < K) {
                    a.v = *(const short8*)__builtin_assume_aligned(ap, 16);
                } else {
#pragma unroll
                    for (int j = 0; j < 8; j++)
                        a.u[j] = ((kb + j) < K) ? ap[j] : 0;
                }
            }
            acc[s][0] = __builtin_amdgcn_mfma_f32_16x16x32_bf16(a.v, b0.v, acc[s][0], 0, 0, 0);
            acc[s][1] = __builtin_amdgcn_mfma_f32_16x16x32_bf16(a.v, b1.v, acc[s][1], 0, 0, 0);
        }
    }

#pragma unroll
    for (int s = 0; s < SUB; s++) {
        const int tile = rg * SUB + s;
        if (tile >= Mtiles) break;
#pragma unroll
        for (int h = 0; h < 2; h++) {
            const int col = c0 + (h << 4) + cl;
            const float bv = HASBIAS ? bias[col] : 0.f;
#pragma unroll
            for (int r = 0; r < 4; r++) {
                const int row = (tile << 4) + (q << 2) + r;   // C/D: row = quad*4 + reg
                float v = acc[s][h][r] + bv;
                if (DOLEAKY) v = leaky_f(v);
                if (OUTF32) ((float*)Cv)[(size_t)row * ldc + col] = v;
                else ((unsigned short*)Cv)[(size_t)row * ldc + col] = f2bf(v);
            }
        }
    }
}

// fp32 -> bf16 weight conversion
__global__ __launch_bounds__(256) void cvt_k(const float* __restrict__ in,
                                             unsigned short* __restrict__ out, int n)
{
    const int i = blockIdx.x * 256 + threadIdx.x;
    if (i < n) out[i] = f2bf(in[i]);
}

__global__ __launch_bounds__(256) void count_k(const int* __restrict__ dst,
                                               const int* __restrict__ et,
                                               int* __restrict__ cnt)
{
    const int e = blockIdx.x * 256 + threadIdx.x;
    if (e >= NE) return;
    atomicAdd(&cnt[et[e] * NN + dst[e]], 1);
}

__global__ __launch_bounds__(256) void invc_k(const int* __restrict__ cnt,
                                              float* __restrict__ invc)
{
    const int i = blockIdx.x * 256 + threadIdx.x;
    if (i >= NR * NN) return;
    const int c = cnt[i];
    invc[i] = 1.0f / (float)(c > 1 ? c : 1);
}

// Repack rgcn_W fp32 [r][k][j] -> bf16 Wp[k][r*128+j] (row-major [128, 1536])
__global__ __launch_bounds__(256) void pack_k(const float* __restrict__ W,
                                              unsigned short* __restrict__ Wp)
{
    const int idx = blockIdx.x * 256 + threadIdx.x;
    if (idx >= NR * NH * NH) return;
    const int r = idx >> 14;
    const int k = (idx >> 7) & 127;
    const int j = idx & 127;
    Wp[(size_t)k * (NR * NH) + r * NH + j] = f2bf(W[idx]);
}

// Per (edge, h): outf[dst, h] += y[src, etype, h] * invcnt[etype, dst]
__global__ __launch_bounds__(256) void scatter_k(
    const unsigned short* __restrict__ y, const int* __restrict__ src,
    const int* __restrict__ dst, const int* __restrict__ et,
    const float* __restrict__ invc, float* __restrict__ outf)
{
    const long long idx = (long long)blockIdx.x * 256 + threadIdx.x;
    const int e = (int)(idx >> 7);
    if (e >= NE) return;
    const int h = (int)(idx & 127);
    const int s = src[e], d = dst[e], r = et[e];
    const float w = invc[r * NN + d];
    const float v = bf2f(y[(size_t)s * (NR * NH) + r * NH + h]) * w;
    atomicAdd(outf + (size_t)d * NH + h, v);
}

__global__ __launch_bounds__(256) void cast_k(const float* __restrict__ in,
                                              unsigned short* __restrict__ out)
{
    const int i = blockIdx.x * 256 + threadIdx.x;
    if (i >= NN * NH) return;
    out[i] = f2bf(in[i]);
}

__global__ __launch_bounds__(256) void final_k(const unsigned short* __restrict__ h,
    const float* __restrict__ W2, const float* __restrict__ b2,
    float* __restrict__ out)
{
    const int idx = blockIdx.x * 256 + threadIdx.x;
    if (idx >= NN * 2) return;
    const int n = idx >> 1, o = idx & 1;
    float acc = b2[o];
    const unsigned short* hr = h + (size_t)n * NH;
    for (int k = 0; k < NH; k++) acc += bf2f(hr[k]) * W2[k * 2 + o];
    out[idx] = acc;
}

extern "C" void kernel_launch(void* const* d_in, const int* in_sizes, int n_in,
                              void* d_out, int out_size, void* d_ws, size_t ws_size,
                              hipStream_t stream)
{
    const float* feat = (const float*)d_in[0];
    const int* ei   = (const int*)d_in[1];
    const int* et   = (const int*)d_in[2];
    const float* Wdes = (const float*)d_in[3];
    const float* bdes = (const float*)d_in[4];
    const float* Wtw  = (const float*)d_in[5];
    const float* btw  = (const float*)d_in[6];
    const float* Wnum = (const float*)d_in[7];
    const float* bnum = (const float*)d_in[8];
    const float* Wcat = (const float*)d_in[9];
    const float* bcat = (const float*)d_in[10];
    const float* Win  = (const float*)d_in[11];
    const float* bin  = (const float*)d_in[12];
    const float* rgW  = (const float*)d_in[13];
    const float* root = (const float*)d_in[14];
    const float* rbias= (const float*)d_in[15];
    const float* Wo1  = (const float*)d_in[16];
    const float* bo1  = (const float*)d_in[17];
    const float* Wo2  = (const float*)d_in[18];
    const float* bo2  = (const float*)d_in[19];
    const int* srcp = ei;
    const int* dstp = ei + NE;

    // Workspace carve (~224 MiB total)
    char* p = (char*)d_ws;
    auto alloc = [&](size_t bytes) { char* r = p; p += (bytes + 255) & ~(size_t)255; return r; };
    unsigned short* xcat = (unsigned short*)alloc((size_t)NN * NH * 2);
    unsigned short* xa   = (unsigned short*)alloc((size_t)NN * NH * 2);
    unsigned short* xb   = (unsigned short*)alloc((size_t)NN * NH * 2);
    unsigned short* y    = (unsigned short*)alloc((size_t)NN * NR * NH * 2);
    float* outf          = (float*)alloc((size_t)NN * NH * 4);
    int* cnt             = (int*)alloc((size_t)NR * NN * 4);
    float* invc          = (float*)alloc((size_t)NR * NN * 4);
    unsigned short* Wp   = (unsigned short*)alloc((size_t)NR * NH * NH * 2);
    unsigned short* bWdes= (unsigned short*)alloc(768 * 32 * 2);
    unsigned short* bWtw = (unsigned short*)alloc(768 * 32 * 2);
    unsigned short* bWnum= (unsigned short*)alloc(34 * 32 * 2);
    unsigned short* bWcat= (unsigned short*)alloc(12 * 32 * 2);
    unsigned short* bWin = (unsigned short*)alloc(NH * NH * 2);
    unsigned short* bRoot= (unsigned short*)alloc(NH * NH * 2);
    unsigned short* bWo1 = (unsigned short*)alloc(NH * NH * 2);

    const int MT = NN / 16;  // 3125 row tiles (exact)

    // Weight conversions (tiny)
    cvt_k<<<(768 * 32 + 255) / 256, 256, 0, stream>>>(Wdes, bWdes, 768 * 32);
    cvt_k<<<(768 * 32 + 255) / 256, 256, 0, stream>>>(Wtw,  bWtw,  768 * 32);
    cvt_k<<<(34 * 32 + 255) / 256, 256, 0, stream>>>(Wnum, bWnum, 34 * 32);
    cvt_k<<<(12 * 32 + 255) / 256, 256, 0, stream>>>(Wcat, bWcat, 12 * 32);
    cvt_k<<<(NH * NH + 255) / 256, 256, 0, stream>>>(Win,  bWin,  NH * NH);
    cvt_k<<<(NH * NH + 255) / 256, 256, 0, stream>>>(root, bRoot, NH * NH);
    cvt_k<<<(NH * NH + 255) / 256, 256, 0, stream>>>(Wo1,  bWo1,  NH * NH);
    pack_k<<<(NR * NH * NH + 255) / 256, 256, 0, stream>>>(rgW, Wp);

    // Edge normalization (shared by both RGCN layers)
    hipMemsetAsync(cnt, 0, (size_t)NR * NN * 4, stream);
    count_k<<<(NE + 255) / 256, 256, 0, stream>>>(dstp, et, cnt);
    invc_k<<<(NR * NN + 255) / 256, 256, 0, stream>>>(cnt, invc);

    // Encoder: 4 block-diagonal GEMMs -> xcat, then W_in -> xa
    {
        dim3 g((MT + 3) / 4, 1);  // SUB=1, fp32 A (feature slices; even offsets => 8B aligned)
        gemm_k<1, true, false, true, true><<<g, 256, 0, stream>>>(feat + 46,  NF, bWdes, 32, bdes, xcat + 0,  NH, MT, 768);
        gemm_k<1, true, false, true, true><<<g, 256, 0, stream>>>(feat + 814, NF, bWtw,  32, btw,  xcat + 32, NH, MT, 768);
        gemm_k<1, true, false, true, true><<<g, 256, 0, stream>>>(feat + 12,  NF, bWnum, 32, bnum, xcat + 64, NH, MT, 34);
        gemm_k<1, true, false, true, true><<<g, 256, 0, stream>>>(feat + 0,   NF, bWcat, 32, bcat, xcat + 96, NH, MT, 12);
    }
    {
        dim3 g((((MT + 1) / 2) + 3) / 4, 4);  // SUB=2, N=128
        gemm_k<2, false, false, true, true><<<g, 256, 0, stream>>>(xcat, NH, bWin, NH, bin, xa, NH, MT, NH);
    }

    // Two RGCN layers
    for (int layer = 0; layer < 2; layer++) {
        const unsigned short* xin = layer ? xb : xa;
        unsigned short* xout      = layer ? xa : xb;
        {
            dim3 g((((MT + 3) / 4) + 3) / 4, 48);  // SUB=4, N=1536
            gemm_k<4, false, false, false, false><<<g, 256, 0, stream>>>(xin, NH, Wp, NR * NH, nullptr, y, NR * NH, MT, NH);
        }
        {
            dim3 g((((MT + 1) / 2) + 3) / 4, 4);   // root + bias, fp32 out
            gemm_k<2, false, true, true, false><<<g, 256, 0, stream>>>(xin, NH, bRoot, NH, rbias, outf, NH, MT, NH);
        }
        scatter_k<<<(int)(((long long)NE * NH + 255) / 256), 256, 0, stream>>>(y, srcp, dstp, et, invc, outf);
        cast_k<<<(NN * NH + 255) / 256, 256, 0, stream>>>(outf, xout);
    }

    // Output head
    {
        dim3 g((((MT + 1) / 2) + 3) / 4, 4);
        gemm_k<2, false, false, true, true><<<g, 256, 0, stream>>>(xa, NH, bWo1, NH, bo1, xb, NH, MT, NH);
    }
    final_k<<<(NN * 2 + 255) / 256, 256, 0, stream>>>(xb, Wo2, bo2, (float*)d_out);
}

// Round 3
// 1100.090 us; speedup vs baseline: 1.4347x; 1.4347x over previous
//
#include <hip/hip_runtime.h>
#include <stdint.h>

// Problem constants
#define NN 50000
#define NE 800000
#define NR 12
#define NH 128
#define NF 1582
#define NSEG (NN * NR)     // 600000 (seg = d*12 + r)
#define KSTK 1664          // stacked K: 1536 (agg) + 128 (x for root)
#define MT 3125            // NN/16 row tiles (exact)
#define SCAN_NB ((NSEG + 255) / 256)   // 2344

typedef __attribute__((ext_vector_type(8))) short short8;   // 8 x bf16
typedef __attribute__((ext_vector_type(4))) float floatx4;  // MFMA acc

__device__ __forceinline__ float bf2f(unsigned int u16) {
    union { unsigned int i; float f; } w; w.i = u16 << 16; return w.f;
}
__device__ __forceinline__ unsigned short f2bf(float f) {
    union { float f; unsigned int i; } w; w.f = f;
    unsigned int i = w.i;
    return (unsigned short)((i + 0x7FFFu + ((i >> 16) & 1u)) >> 16);  // RNE
}
__device__ __forceinline__ float leaky_f(float v) { return v > 0.f ? v : 0.01f * v; }

// ---------------- weight pre-swizzle into MFMA B-fragment order ----------------
// dst[((ct*KS+ks)*64 + lane)*8 + j] = src[k*N + col], k = ks*32+(lane>>4)*8+j,
// col = ct*16+(lane&15); rows >= K1 read src2 (stack), rows >= Ktot are zero (pad).
__global__ __launch_bounds__(256) void swz_k(
    const float* __restrict__ src1, int K1,
    const float* __restrict__ src2, int Ktot, int N, int KS,
    unsigned short* __restrict__ dst)
{
    const int idx = blockIdx.x * 256 + threadIdx.x;
    const int total = (N >> 4) * KS * 512;
    if (idx >= total) return;
    const int j = idx & 7;
    const int lane = (idx >> 3) & 63;
    const int cks = idx >> 9;
    const int ks = cks % KS;
    const int ct = cks / KS;
    const int k = ks * 32 + (lane >> 4) * 8 + j;
    const int col = ct * 16 + (lane & 15);
    float v = 0.f;
    if (k < Ktot) v = (k < K1) ? src1[(size_t)k * N + col] : src2[(size_t)(k - K1) * N + col];
    dst[idx] = f2bf(v);
}

// ---------------- CSR build: histogram, 3-pass scan, fill ----------------
__global__ __launch_bounds__(256) void hist_k(const int* __restrict__ dst,
                                              const int* __restrict__ et,
                                              int* __restrict__ deg)
{
    const int e = blockIdx.x * 256 + threadIdx.x;
    if (e >= NE) return;
    atomicAdd(&deg[dst[e] * NR + et[e]], 1);
}

__global__ __launch_bounds__(256) void scanA_k(const int* __restrict__ deg,
                                               int* __restrict__ offs,
                                               int* __restrict__ part)
{
    __shared__ int lds[256];
    const int i = blockIdx.x * 256 + threadIdx.x;
    const int v = (i < NSEG) ? deg[i] : 0;
    lds[threadIdx.x] = v; __syncthreads();
#pragma unroll
    for (int d = 1; d < 256; d <<= 1) {
        const int t = (threadIdx.x >= d) ? lds[threadIdx.x - d] : 0;
        __syncthreads();
        lds[threadIdx.x] += t;
        __syncthreads();
    }
    if (i < NSEG) offs[i] = lds[threadIdx.x] - v;   // exclusive within block
    if (threadIdx.x == 255) part[blockIdx.x] = lds[255];
}

__global__ __launch_bounds__(256) void scanB_k(int* __restrict__ part, int nb)
{
    __shared__ int lds[256];
    __shared__ int carry;
    if (threadIdx.x == 0) carry = 0;
    __syncthreads();
    for (int base = 0; base < nb; base += 256) {
        const int i = base + threadIdx.x;
        const int v = (i < nb) ? part[i] : 0;
        lds[threadIdx.x] = v; __syncthreads();
#pragma unroll
        for (int d = 1; d < 256; d <<= 1) {
            const int t = (threadIdx.x >= d) ? lds[threadIdx.x - d] : 0;
            __syncthreads();
            lds[threadIdx.x] += t;
            __syncthreads();
        }
        if (i < nb) part[i] = lds[threadIdx.x] - v + carry;  // exclusive + carry
        __syncthreads();
        if (threadIdx.x == 255) carry += lds[255];
        __syncthreads();
    }
}

__global__ __launch_bounds__(256) void scanC_k(int* __restrict__ offs,
                                               const int* __restrict__ part)
{
    const int i = blockIdx.x * 256 + threadIdx.x;
    if (i < NSEG) offs[i] += part[blockIdx.x];
}

__global__ __launch_bounds__(256) void fill_k(const int* __restrict__ src,
                                              const int* __restrict__ dst,
                                              const int* __restrict__ et,
                                              const int* __restrict__ offs,
                                              int* __restrict__ cur,
                                              unsigned int* __restrict__ eidx)
{
    const int e = blockIdx.x * 256 + threadIdx.x;
    if (e >= NE) return;
    const int s = dst[e] * NR + et[e];
    const int pos = offs[s] + atomicAdd(&cur[s], 1);
    eidx[pos] = (unsigned int)src[e];
}

// ---------------- per-segment mean aggregation (wave per seg) ----------------
// Sx row for node d: cols [0,1536) = agg (seg-major), cols [1536,1664) = x (filled by copyx_k)
__global__ __launch_bounds__(256) void agg_k(const unsigned short* __restrict__ x,
                                             const unsigned int* __restrict__ eidx,
                                             const int* __restrict__ offs,
                                             const int* __restrict__ deg,
                                             unsigned short* __restrict__ Sx)
{
    const int wave = threadIdx.x >> 6, lane = threadIdx.x & 63;
    const int s = blockIdx.x * 4 + wave;
    if (s >= NSEG) return;
    const int beg = offs[s], n = deg[s];
    float a0 = 0.f, a1 = 0.f;
    for (int e = 0; e < n; e++) {
        const unsigned int srci = eidx[beg + e];
        const unsigned int v = *(const unsigned int*)(x + (size_t)srci * NH + 2 * lane);
        a0 += bf2f(v & 0xFFFFu);
        a1 += bf2f(v >> 16);
    }
    const float w = 1.0f / (float)(n > 1 ? n : 1);
    const unsigned int o = (unsigned int)f2bf(a0 * w) | ((unsigned int)f2bf(a1 * w) << 16);
    const int d = s / NR, r = s % NR;
    *(unsigned int*)(Sx + (size_t)d * KSTK + r * NH + 2 * lane) = o;
}

__global__ __launch_bounds__(256) void copyx_k(const unsigned short* __restrict__ x,
                                               unsigned short* __restrict__ Sx)
{
    const int i = blockIdx.x * 256 + threadIdx.x;     // NN*64 u32 copies
    if (i >= NN * 64) return;
    const int d = i >> 6, l = i & 63;
    *(unsigned int*)(Sx + (size_t)d * KSTK + 1536 + 2 * l) =
        *(const unsigned int*)(x + (size_t)d * NH + 2 * l);
}

// ---------------- MFMA GEMM with pre-swizzled B ----------------
// C[M, CT*16] = act(A[M,K] @ B + bias), A fp32 (AF32) or bf16, M = MT*16.
// Wave: SUB row-tiles x CT col-tiles. Grid: ceil(ceil(MT/SUB)/4) blocks of 4 waves.
template<int SUB, int CT, bool AF32, bool DOLEAKY>
__global__ __launch_bounds__(256) void gemm2_k(
    const void* __restrict__ Av, int lda,
    const unsigned short* __restrict__ Bs,
    const float* __restrict__ bias,
    unsigned short* __restrict__ C, int ldc,
    int K, int KS)
{
    const int wave = threadIdx.x >> 6, lane = threadIdx.x & 63;
    const int q = lane >> 4, cl = lane & 15;
    const int RG = (MT + SUB - 1) / SUB;
    const int rg = blockIdx.x * 4 + wave;
    if (rg >= RG) return;

    floatx4 acc[SUB][CT];
#pragma unroll
    for (int s = 0; s < SUB; s++)
#pragma unroll
        for (int ct = 0; ct < CT; ct++) {
            floatx4 z = {0.f, 0.f, 0.f, 0.f};
            acc[s][ct] = z;
        }

    for (int ks = 0; ks < KS; ks++) {
        const int kb = ks * 32 + q * 8;
        short8 b[CT];
#pragma unroll
        for (int ct = 0; ct < CT; ct++)
            b[ct] = *(const short8*)(Bs + ((size_t)(ct * KS + ks) * 64 + lane) * 8);
#pragma unroll
        for (int s = 0; s < SUB; s++) {
            const int tile = rg * SUB + s;
            if (tile < MT) {
                const int row = tile * 16 + cl;
                union { short8 v; unsigned short u[8]; } a;
                if constexpr (AF32) {
                    const float* ap = (const float*)Av + (size_t)row * lda + kb;
                    if (kb + 7 < K) {
#pragma unroll
                        for (int j = 0; j < 4; j++) {
                            const float2 t = *(const float2*)__builtin_assume_aligned(ap + 2 * j, 8);
                            a.u[2 * j]     = f2bf(t.x);
                            a.u[2 * j + 1] = f2bf(t.y);
                        }
                    } else {
#pragma unroll
                        for (int j = 0; j < 8; j++)
                            a.u[j] = ((kb + j) < K) ? f2bf(ap[j]) : 0;
                    }
                } else {
                    a.v = *(const short8*)__builtin_assume_aligned(
                        (const unsigned short*)Av + (size_t)row * lda + kb, 16);
                }
#pragma unroll
                for (int ct = 0; ct < CT; ct++)
                    acc[s][ct] = __builtin_amdgcn_mfma_f32_16x16x32_bf16(a.v, b[ct], acc[s][ct], 0, 0, 0);
            }
        }
    }

#pragma unroll
    for (int s = 0; s < SUB; s++) {
        const int tile = rg * SUB + s;
        if (tile >= MT) continue;
#pragma unroll
        for (int ct = 0; ct < CT; ct++) {
            const int col = ct * 16 + cl;
            const float bv = bias[col];
#pragma unroll
            for (int r = 0; r < 4; r++) {
                const int row = tile * 16 + q * 4 + r;   // C/D: row = quad*4 + reg
                float v = acc[s][ct][r] + bv;
                if (DOLEAKY) v = leaky_f(v);
                C[(size_t)row * ldc + col] = f2bf(v);
            }
        }
    }
}

// ---------------- tiny output head ----------------
__global__ __launch_bounds__(256) void final_k(const unsigned short* __restrict__ h,
    const float* __restrict__ W2, const float* __restrict__ b2,
    float* __restrict__ out)
{
    const int idx = blockIdx.x * 256 + threadIdx.x;
    if (idx >= NN * 2) return;
    const int n = idx >> 1, o = idx & 1;
    float acc = b2[o];
    const unsigned short* hr = h + (size_t)n * NH;
    for (int k = 0; k < NH; k++) acc += bf2f(hr[k]) * W2[k * 2 + o];
    out[idx] = acc;
}

extern "C" void kernel_launch(void* const* d_in, const int* in_sizes, int n_in,
                              void* d_out, int out_size, void* d_ws, size_t ws_size,
                              hipStream_t stream)
{
    const float* feat = (const float*)d_in[0];
    const int* ei   = (const int*)d_in[1];
    const int* et   = (const int*)d_in[2];
    const float* Wdes = (const float*)d_in[3];
    const float* bdes = (const float*)d_in[4];
    const float* Wtw  = (const float*)d_in[5];
    const float* btw  = (const float*)d_in[6];
    const float* Wnum = (const float*)d_in[7];
    const float* bnum = (const float*)d_in[8];
    const float* Wcat = (const float*)d_in[9];
    const float* bcat = (const float*)d_in[10];
    const float* Win  = (const float*)d_in[11];
    const float* bin  = (const float*)d_in[12];
    const float* rgW  = (const float*)d_in[13];
    const float* root = (const float*)d_in[14];
    const float* rbias= (const float*)d_in[15];
    const float* Wo1  = (const float*)d_in[16];
    const float* bo1  = (const float*)d_in[17];
    const float* Wo2  = (const float*)d_in[18];
    const float* bo2  = (const float*)d_in[19];
    const int* srcp = ei;
    const int* dstp = ei + NE;

    // Workspace carve (~216 MiB)
    char* p = (char*)d_ws;
    auto alloc = [&](size_t bytes) { char* r = p; p += (bytes + 255) & ~(size_t)255; return r; };
    unsigned short* xcat = (unsigned short*)alloc((size_t)NN * NH * 2);
    unsigned short* xa   = (unsigned short*)alloc((size_t)NN * NH * 2);
    unsigned short* xb   = (unsigned short*)alloc((size_t)NN * NH * 2);
    unsigned short* Sx   = (unsigned short*)alloc((size_t)NN * KSTK * 2);   // 166.4 MB
    int* deg  = (int*)alloc((size_t)NSEG * 4);
    int* offs = (int*)alloc((size_t)NSEG * 4);
    int* cur  = (int*)alloc((size_t)NSEG * 4);
    int* part = (int*)alloc((size_t)(SCAN_NB + 8) * 4);
    unsigned int* eidx = (unsigned int*)alloc((size_t)NE * 4);
    unsigned short* sWdes = (unsigned short*)alloc((size_t)2 * 24 * 512 * 2);
    unsigned short* sWtw  = (unsigned short*)alloc((size_t)2 * 24 * 512 * 2);
    unsigned short* sWnum = (unsigned short*)alloc((size_t)2 * 2 * 512 * 2);
    unsigned short* sWcat = (unsigned short*)alloc((size_t)2 * 1 * 512 * 2);
    unsigned short* sWin  = (unsigned short*)alloc((size_t)8 * 4 * 512 * 2);
    unsigned short* sWstk = (unsigned short*)alloc((size_t)8 * 52 * 512 * 2);
    unsigned short* sWo1  = (unsigned short*)alloc((size_t)8 * 4 * 512 * 2);

    const int GB = (((MT + 1) / 2) + 3) / 4;  // 391 blocks for SUB=2

    // CSR build (shared by both layers)
    hipMemsetAsync(deg, 0, (size_t)NSEG * 4, stream);
    hipMemsetAsync(cur, 0, (size_t)NSEG * 4, stream);
    hist_k<<<(NE + 255) / 256, 256, 0, stream>>>(dstp, et, deg);
    scanA_k<<<SCAN_NB, 256, 0, stream>>>(deg, offs, part);
    scanB_k<<<1, 256, 0, stream>>>(part, SCAN_NB);
    scanC_k<<<SCAN_NB, 256, 0, stream>>>(offs, part);
    fill_k<<<(NE + 255) / 256, 256, 0, stream>>>(srcp, dstp, et, offs, cur, eidx);

    // Weight swizzles
    auto swz = [&](const float* s1, int K1, const float* s2, int Ktot, int N,
                   unsigned short* dstp_) {
        const int KS = (Ktot + 31) / 32;
        const int total = (N / 16) * KS * 512;
        swz_k<<<(total + 255) / 256, 256, 0, stream>>>(s1, K1, s2, Ktot, N, KS, dstp_);
    };
    swz(Wdes, 768, Wdes, 768, 32, sWdes);
    swz(Wtw,  768, Wtw,  768, 32, sWtw);
    swz(Wnum,  34, Wnum,  34, 32, sWnum);
    swz(Wcat,  12, Wcat,  12, 32, sWcat);
    swz(Win,  128, Win,  128, 128, sWin);
    swz(rgW, 1536, root, KSTK, 128, sWstk);   // stacked [rgW_flat ; root]
    swz(Wo1,  128, Wo1,  128, 128, sWo1);

    // Encoder: 4 block-diagonal GEMMs -> xcat, then W_in -> xa
    gemm2_k<2, 2, true, true><<<GB, 256, 0, stream>>>(feat + 46,  NF, sWdes, bdes, xcat + 0,  NH, 768, 24);
    gemm2_k<2, 2, true, true><<<GB, 256, 0, stream>>>(feat + 814, NF, sWtw,  btw,  xcat + 32, NH, 768, 24);
    gemm2_k<2, 2, true, true><<<GB, 256, 0, stream>>>(feat + 12,  NF, sWnum, bnum, xcat + 64, NH, 34, 2);
    gemm2_k<2, 2, true, true><<<GB, 256, 0, stream>>>(feat + 0,   NF, sWcat, bcat, xcat + 96, NH, 12, 1);
    gemm2_k<2, 8, false, true><<<GB, 256, 0, stream>>>(xcat, NH, sWin, bin, xa, NH, 128, 4);

    // Two RGCN layers: aggregate-then-transform (stacked with root)
    for (int layer = 0; layer < 2; layer++) {
        const unsigned short* xin = layer ? xb : xa;
        unsigned short* xout      = layer ? xa : xb;
        agg_k<<<(NSEG + 3) / 4, 256, 0, stream>>>(xin, eidx, offs, deg, Sx);
        copyx_k<<<(NN * 64 + 255) / 256, 256, 0, stream>>>(xin, Sx);
        gemm2_k<2, 8, false, false><<<GB, 256, 0, stream>>>(Sx, KSTK, sWstk, rbias, xout, NH, KSTK, 52);
    }

    // Output head
    gemm2_k<2, 8, false, true><<<GB, 256, 0, stream>>>(xa, NH, sWo1, bo1, xb, NH, 128, 4);
    final_k<<<(NN * 2 + 255) / 256, 256, 0, stream>>>(xb, Wo2, bo2, (float*)d_out);
}

// Round 4
// 936.393 us; speedup vs baseline: 1.6855x; 1.1748x over previous
//
#include <hip/hip_runtime.h>
#include <stdint.h>

// Problem constants
#define NN 50000
#define NE 800000
#define NR 12
#define NH 128
#define NF 1582
#define NSEG (NN * NR)        // 600000 (seg = d*12 + r)
#define MT 3125               // NN/16 row tiles (exact)
#define SCAN_NB ((NSEG + 255) / 256)   // 2344
#define KSENC 50              // ceil(1582/32)
#define KSSTK 52              // 1664/32 (12*128 agg + 128 root)

typedef __attribute__((ext_vector_type(8))) short short8;   // 8 x bf16
typedef __attribute__((ext_vector_type(4))) float floatx4;  // MFMA acc

__device__ __forceinline__ float bf2f(unsigned int u16) {
    union { unsigned int i; float f; } w; w.i = u16 << 16; return w.f;
}
__device__ __forceinline__ unsigned short f2bf(float f) {
    union { float f; unsigned int i; } w; w.f = f;
    unsigned int i = w.i;
    return (unsigned short)((i + 0x7FFFu + ((i >> 16) & 1u)) >> 16);  // RNE
}
__device__ __forceinline__ float leaky_f(float v) { return v > 0.f ? v : 0.01f * v; }

// ================= weight swizzles into MFMA B-fragment order =================
// layout: dst[((ct*KS+ks)*64+lane)*8 + j] = B[k][col], k=ks*32+(lane>>4)*8+j,
// col=ct*16+(lane&15). Zero outside valid k. (proven in round 3)
__global__ __launch_bounds__(256) void swz_k(
    const float* __restrict__ src1, int K1,
    const float* __restrict__ src2, int Ktot, int N, int KS,
    unsigned short* __restrict__ dst)
{
    const int idx = blockIdx.x * 256 + threadIdx.x;
    const int total = (N >> 4) * KS * 512;
    if (idx >= total) return;
    const int j = idx & 7;
    const int lane = (idx >> 3) & 63;
    const int cks = idx >> 9;
    const int ks = cks % KS;
    const int ct = cks / KS;
    const int k = ks * 32 + (lane >> 4) * 8 + j;
    const int col = ct * 16 + (lane & 15);
    float v = 0.f;
    if (k < Ktot) v = (k < K1) ? src1[(size_t)k * N + col] : src2[(size_t)(k - K1) * N + col];
    dst[idx] = f2bf(v);
}

// Encoder block-diagonal B [1582(pad 1600) x 128]:
// cols 0..31: Wdes rows 46..814 | 32..63: Wtw rows 814..1582
// cols 64..95: Wnum rows 12..46 | 96..127: Wcat rows 0..12
__global__ __launch_bounds__(256) void swzenc_k(
    const float* __restrict__ Wdes, const float* __restrict__ Wtw,
    const float* __restrict__ Wnum, const float* __restrict__ Wcat,
    unsigned short* __restrict__ dst)
{
    const int idx = blockIdx.x * 256 + threadIdx.x;
    const int total = 8 * KSENC * 512;
    if (idx >= total) return;
    const int j = idx & 7;
    const int lane = (idx >> 3) & 63;
    const int cks = idx >> 9;
    const int ks = cks % KSENC;
    const int ct = cks / KSENC;
    const int k = ks * 32 + (lane >> 4) * 8 + j;
    const int col = ct * 16 + (lane & 15);
    float v = 0.f;
    if (col < 32) {
        if (k >= 46 && k < 814)   v = Wdes[(size_t)(k - 46) * 32 + col];
    } else if (col < 64) {
        if (k >= 814 && k < 1582) v = Wtw[(size_t)(k - 814) * 32 + (col - 32)];
    } else if (col < 96) {
        if (k >= 12 && k < 46)    v = Wnum[(size_t)(k - 12) * 32 + (col - 64)];
    } else {
        if (k < 12)               v = Wcat[(size_t)k * 32 + (col - 96)];
    }
    dst[idx] = f2bf(v);
}

__global__ __launch_bounds__(128) void packbias_k(
    const float* __restrict__ bdes, const float* __restrict__ btw,
    const float* __restrict__ bnum, const float* __restrict__ bcat,
    float* __restrict__ be)
{
    const int c = threadIdx.x;
    float v;
    if (c < 32) v = bdes[c];
    else if (c < 64) v = btw[c - 32];
    else if (c < 96) v = bnum[c - 64];
    else v = bcat[c - 96];
    be[c] = v;
}

// ================= CSR build =================
__global__ __launch_bounds__(256) void hist_k(const int* __restrict__ dst,
                                              const int* __restrict__ et,
                                              int* __restrict__ deg)
{
    const int e = blockIdx.x * 256 + threadIdx.x;
    if (e >= NE) return;
    atomicAdd(&deg[dst[e] * NR + et[e]], 1);
}

__global__ __launch_bounds__(256) void scanA_k(const int* __restrict__ deg,
                                               int* __restrict__ offs,
                                               int* __restrict__ part)
{
    __shared__ int lds[256];
    const int i = blockIdx.x * 256 + threadIdx.x;
    const int v = (i < NSEG) ? deg[i] : 0;
    lds[threadIdx.x] = v; __syncthreads();
#pragma unroll
    for (int d = 1; d < 256; d <<= 1) {
        const int t = (threadIdx.x >= d) ? lds[threadIdx.x - d] : 0;
        __syncthreads();
        lds[threadIdx.x] += t;
        __syncthreads();
    }
    if (i < NSEG) offs[i] = lds[threadIdx.x] - v;
    if (threadIdx.x == 255) part[blockIdx.x] = lds[255];
}

__global__ __launch_bounds__(256) void scanB_k(int* __restrict__ part, int nb)
{
    __shared__ int lds[256];
    __shared__ int carry;
    if (threadIdx.x == 0) carry = 0;
    __syncthreads();
    for (int base = 0; base < nb; base += 256) {
        const int i = base + threadIdx.x;
        const int v = (i < nb) ? part[i] : 0;
        lds[threadIdx.x] = v; __syncthreads();
#pragma unroll
        for (int d = 1; d < 256; d <<= 1) {
            const int t = (threadIdx.x >= d) ? lds[threadIdx.x - d] : 0;
            __syncthreads();
            lds[threadIdx.x] += t;
            __syncthreads();
        }
        if (i < nb) part[i] = lds[threadIdx.x] - v + carry;
        __syncthreads();
        if (threadIdx.x == 255) carry += lds[255];
        __syncthreads();
    }
}

__global__ __launch_bounds__(256) void scanC_k(int* __restrict__ offs,
                                               const int* __restrict__ part)
{
    const int i = blockIdx.x * 256 + threadIdx.x;
    if (i < NSEG) offs[i] += part[blockIdx.x];
}

__global__ __launch_bounds__(256) void fill_k(const int* __restrict__ src,
                                              const int* __restrict__ dst,
                                              const int* __restrict__ et,
                                              const int* __restrict__ offs,
                                              int* __restrict__ cur,
                                              unsigned int* __restrict__ eidx)
{
    const int e = blockIdx.x * 256 + threadIdx.x;
    if (e >= NE) return;
    const int s = dst[e] * NR + et[e];
    const int pos = offs[s] + atomicAdd(&cur[s], 1);
    eidx[pos] = (unsigned int)src[e];
}

// ================= fused encoder: feat -> blockdiag GEMM -> leaky -> W_in -> xa ===========
__global__ __launch_bounds__(256) void enc_k(
    const float* __restrict__ feat,
    const unsigned short* __restrict__ Benc, const float* __restrict__ be,
    const unsigned short* __restrict__ Bwin, const float* __restrict__ bin,
    unsigned short* __restrict__ xa)
{
    const int wave = threadIdx.x >> 6, lane = threadIdx.x & 63;
    const int q = lane >> 4, cl = lane & 15;
    int tile = blockIdx.x * 4 + wave;
    if (tile >= MT) tile = MT - 1;          // duplicate work; identical stores (benign)
    const int row = tile * 16 + cl;

    // active ks ranges per col-tile: des[46,814) tw[814,1582) num[12,46) cat[0,12)
    const int lo[8] = {1, 1, 25, 25, 0, 0, 0, 0};
    const int hi[8] = {26, 26, 50, 50, 2, 2, 1, 1};

    floatx4 acc[8];
#pragma unroll
    for (int ct = 0; ct < 8; ct++) { floatx4 z = {0.f,0.f,0.f,0.f}; acc[ct] = z; }

    for (int ks = 0; ks < KSENC; ks++) {
        const int kb = ks * 32 + q * 8;
        union { short8 v; unsigned short u[8]; } a;
        const float* ap = feat + (size_t)row * NF + kb;
        if (kb + 7 < NF) {
#pragma unroll
            for (int j = 0; j < 4; j++) {
                const float2 t = *(const float2*)__builtin_assume_aligned(ap + 2 * j, 8);
                a.u[2 * j]     = f2bf(t.x);
                a.u[2 * j + 1] = f2bf(t.y);
            }
        } else {
#pragma unroll
            for (int j = 0; j < 8; j++)
                a.u[j] = ((kb + j) < NF) ? f2bf(ap[j]) : 0;
        }
#pragma unroll
        for (int ct = 0; ct < 8; ct++) {
            if (ks >= lo[ct] && ks < hi[ct]) {
                const short8 b = *(const short8*)(Benc + ((size_t)(ct * KSENC + ks) * 64 + lane) * 8);
                acc[ct] = __builtin_amdgcn_mfma_f32_16x16x32_bf16(a.v, b, acc[ct], 0, 0, 0);
            }
        }
    }

    // leaky(acc + bias) -> LDS tile (C-layout -> A-layout transpose)
    __shared__ unsigned short lds[4][16][136];   // +8 pad: 2-way banks only
#pragma unroll
    for (int ct = 0; ct < 8; ct++) {
        const int col = ct * 16 + cl;
        const float bv = be[col];
#pragma unroll
        for (int r = 0; r < 4; r++)
            lds[wave][q * 4 + r][col] = f2bf(leaky_f(acc[ct][r] + bv));
    }
    __syncthreads();   // all 256 threads active (tile clamped)

    // W_in stage: A from LDS
    floatx4 acc2[8];
#pragma unroll
    for (int ct = 0; ct < 8; ct++) { floatx4 z = {0.f,0.f,0.f,0.f}; acc2[ct] = z; }
#pragma unroll
    for (int ks2 = 0; ks2 < 4; ks2++) {
        const short8 a2 = *(const short8*)&lds[wave][cl][ks2 * 32 + q * 8];
#pragma unroll
        for (int ct = 0; ct < 8; ct++) {
            const short8 b = *(const short8*)(Bwin + ((size_t)(ct * 4 + ks2) * 64 + lane) * 8);
            acc2[ct] = __builtin_amdgcn_mfma_f32_16x16x32_bf16(a2, b, acc2[ct], 0, 0, 0);
        }
    }
#pragma unroll
    for (int ct = 0; ct < 8; ct++) {
        const int col = ct * 16 + cl;
        const float bv = bin[col];
#pragma unroll
        for (int r = 0; r < 4; r++)
            xa[(size_t)(tile * 16 + q * 4 + r) * NH + col] = f2bf(leaky_f(acc2[ct][r] + bv));
    }
}

// ============ fused RGCN layer: gather-mean into A-fragments + stacked GEMM ============
// out[d] = sum_r mean_{nb in N_r(d)} x[nb] @ W_r  +  x[d] @ root  + bias
__global__ __launch_bounds__(256) void layer_k(
    const unsigned short* __restrict__ xin,
    const unsigned int* __restrict__ eidx,
    const int* __restrict__ offs, const int* __restrict__ deg,
    const unsigned short* __restrict__ Bstk, const float* __restrict__ rbias,
    unsigned short* __restrict__ xout)
{
    const int wave = threadIdx.x >> 6, lane = threadIdx.x & 63;
    const int q = lane >> 4, cl = lane & 15;
    const int tile = blockIdx.x * 4 + wave;
    if (tile >= MT) return;                  // no LDS/barrier in this kernel
    const int d = tile * 16 + cl;

    floatx4 acc[8];
#pragma unroll
    for (int ct = 0; ct < 8; ct++) { floatx4 z = {0.f,0.f,0.f,0.f}; acc[ct] = z; }

    // aggregated part: r = 0..11, each covers ks = r*4 .. r*4+3 (k = r*128 + ki*32 + q*8 + j)
    for (int r = 0; r < NR; r++) {
        const int seg = d * NR + r;
        const int beg = offs[seg];
        const int n = deg[seg];
        float f[4][8];
#pragma unroll
        for (int ki = 0; ki < 4; ki++)
#pragma unroll
            for (int m = 0; m < 8; m++) f[ki][m] = 0.f;

        for (int e = 0; e < n; e++) {
            const unsigned int nb = eidx[beg + e];
            const unsigned short* xr = xin + (size_t)nb * NH + q * 8;
#pragma unroll
            for (int ki = 0; ki < 4; ki++) {
                const uint4 t = *(const uint4*)(xr + ki * 32);
                f[ki][0] += bf2f(t.x & 0xFFFFu); f[ki][1] += bf2f(t.x >> 16);
                f[ki][2] += bf2f(t.y & 0xFFFFu); f[ki][3] += bf2f(t.y >> 16);
                f[ki][4] += bf2f(t.z & 0xFFFFu); f[ki][5] += bf2f(t.z >> 16);
                f[ki][6] += bf2f(t.w & 0xFFFFu); f[ki][7] += bf2f(t.w >> 16);
            }
        }
        const float w = 1.0f / (float)(n > 1 ? n : 1);
#pragma unroll
        for (int ki = 0; ki < 4; ki++) {
            union { short8 v; unsigned short u[8]; } a;
#pragma unroll
            for (int m = 0; m < 8; m++) a.u[m] = f2bf(f[ki][m] * w);
            const int ks = r * 4 + ki;
#pragma unroll
            for (int ct = 0; ct < 8; ct++) {
                const short8 b = *(const short8*)(Bstk + ((size_t)(ct * KSSTK + ks) * 64 + lane) * 8);
                acc[ct] = __builtin_amdgcn_mfma_f32_16x16x32_bf16(a.v, b, acc[ct], 0, 0, 0);
            }
        }
    }

    // root part: ks = 48..51, A = xin[d] directly
#pragma unroll
    for (int ki = 0; ki < 4; ki++) {
        const short8 a = *(const short8*)__builtin_assume_aligned(
            xin + (size_t)d * NH + ki * 32 + q * 8, 16);
        const int ks = 48 + ki;
#pragma unroll
        for (int ct = 0; ct < 8; ct++) {
            const short8 b = *(const short8*)(Bstk + ((size_t)(ct * KSSTK + ks) * 64 + lane) * 8);
            acc[ct] = __builtin_amdgcn_mfma_f32_16x16x32_bf16(a, b, acc[ct], 0, 0, 0);
        }
    }

#pragma unroll
    for (int ct = 0; ct < 8; ct++) {
        const int col = ct * 16 + cl;
        const float bv = rbias[col];
#pragma unroll
        for (int r2 = 0; r2 < 4; r2++)
            xout[(size_t)(tile * 16 + q * 4 + r2) * NH + col] = f2bf(acc[ct][r2] + bv);
    }
}

// ============ fused head: leaky(xa@Wo1+b) then @Wo2+b2 -> out ============
__global__ __launch_bounds__(256) void head_k(
    const unsigned short* __restrict__ xa,
    const unsigned short* __restrict__ Bo1, const float* __restrict__ bo1,
    const float* __restrict__ Wo2, const float* __restrict__ bo2,
    float* __restrict__ out)
{
    const int wave = threadIdx.x >> 6, lane = threadIdx.x & 63;
    const int q = lane >> 4, cl = lane & 15;
    int tile = blockIdx.x * 4 + wave;
    if (tile >= MT) tile = MT - 1;           // clamp; duplicate identical stores

    floatx4 acc[8];
#pragma unroll
    for (int ct = 0; ct < 8; ct++) { floatx4 z = {0.f,0.f,0.f,0.f}; acc[ct] = z; }
#pragma unroll
    for (int ks = 0; ks < 4; ks++) {
        const short8 a = *(const short8*)__builtin_assume_aligned(
            xa + (size_t)(tile * 16 + cl) * NH + ks * 32 + q * 8, 16);
#pragma unroll
        for (int ct = 0; ct < 8; ct++) {
            const short8 b = *(const short8*)(Bo1 + ((size_t)(ct * 4 + ks) * 64 + lane) * 8);
            acc[ct] = __builtin_amdgcn_mfma_f32_16x16x32_bf16(a, b, acc[ct], 0, 0, 0);
        }
    }
    __shared__ unsigned short lds[4][16][136];
#pragma unroll
    for (int ct = 0; ct < 8; ct++) {
        const int col = ct * 16 + cl;
        const float bv = bo1[col];
#pragma unroll
        for (int r = 0; r < 4; r++)
            lds[wave][q * 4 + r][col] = f2bf(leaky_f(acc[ct][r] + bv));
    }
    __syncthreads();

    if (lane < 32) {
        const int row = lane >> 1, o = lane & 1;
        float s = bo2[o];
        for (int k = 0; k < NH; k++)
            s += bf2f(lds[wave][row][k]) * Wo2[k * 2 + o];
        out[(size_t)(tile * 16 + row) * 2 + o] = s;
    }
}

extern "C" void kernel_launch(void* const* d_in, const int* in_sizes, int n_in,
                              void* d_out, int out_size, void* d_ws, size_t ws_size,
                              hipStream_t stream)
{
    const float* feat = (const float*)d_in[0];
    const int* ei   = (const int*)d_in[1];
    const int* et   = (const int*)d_in[2];
    const float* Wdes = (const float*)d_in[3];
    const float* bdes = (const float*)d_in[4];
    const float* Wtw  = (const float*)d_in[5];
    const float* btw  = (const float*)d_in[6];
    const float* Wnum = (const float*)d_in[7];
    const float* bnum = (const float*)d_in[8];
    const float* Wcat = (const float*)d_in[9];
    const float* bcat = (const float*)d_in[10];
    const float* Win  = (const float*)d_in[11];
    const float* bin  = (const float*)d_in[12];
    const float* rgW  = (const float*)d_in[13];
    const float* root = (const float*)d_in[14];
    const float* rbias= (const float*)d_in[15];
    const float* Wo1  = (const float*)d_in[16];
    const float* bo1  = (const float*)d_in[17];
    const float* Wo2  = (const float*)d_in[18];
    const float* bo2  = (const float*)d_in[19];
    const int* srcp = ei;
    const int* dstp = ei + NE;

    // Workspace carve (~45 MiB)
    char* p = (char*)d_ws;
    auto alloc = [&](size_t bytes) { char* r = p; p += (bytes + 255) & ~(size_t)255; return r; };
    unsigned short* xa = (unsigned short*)alloc((size_t)NN * NH * 2);
    unsigned short* xb = (unsigned short*)alloc((size_t)NN * NH * 2);
    int* deg  = (int*)alloc((size_t)NSEG * 4);
    int* offs = (int*)alloc((size_t)NSEG * 4);
    int* cur  = (int*)alloc((size_t)NSEG * 4);
    int* part = (int*)alloc((size_t)(SCAN_NB + 8) * 4);
    unsigned int* eidx = (unsigned int*)alloc((size_t)NE * 4);
    unsigned short* Benc = (unsigned short*)alloc((size_t)8 * KSENC * 512 * 2);
    unsigned short* sWin = (unsigned short*)alloc((size_t)8 * 4 * 512 * 2);
    unsigned short* sWstk= (unsigned short*)alloc((size_t)8 * KSSTK * 512 * 2);
    unsigned short* sWo1 = (unsigned short*)alloc((size_t)8 * 4 * 512 * 2);
    float* be = (float*)alloc(128 * 4);

    const int GB = (MT + 3) / 4;   // 782 blocks of 4 waves

    // CSR build
    hipMemsetAsync(deg, 0, (size_t)NSEG * 4, stream);
    hipMemsetAsync(cur, 0, (size_t)NSEG * 4, stream);
    hist_k<<<(NE + 255) / 256, 256, 0, stream>>>(dstp, et, deg);
    scanA_k<<<SCAN_NB, 256, 0, stream>>>(deg, offs, part);
    scanB_k<<<1, 256, 0, stream>>>(part, SCAN_NB);
    scanC_k<<<SCAN_NB, 256, 0, stream>>>(offs, part);
    fill_k<<<(NE + 255) / 256, 256, 0, stream>>>(srcp, dstp, et, offs, cur, eidx);

    // Weight prep
    swzenc_k<<<(8 * KSENC * 512 + 255) / 256, 256, 0, stream>>>(Wdes, Wtw, Wnum, Wcat, Benc);
    packbias_k<<<1, 128, 0, stream>>>(bdes, btw, bnum, bcat, be);
    swz_k<<<(8 * 4 * 512 + 255) / 256, 256, 0, stream>>>(Win, 128, Win, 128, 128, 4, sWin);
    swz_k<<<(8 * KSSTK * 512 + 255) / 256, 256, 0, stream>>>(rgW, 1536, root, 1664, 128, KSSTK, sWstk);
    swz_k<<<(8 * 4 * 512 + 255) / 256, 256, 0, stream>>>(Wo1, 128, Wo1, 128, 128, 4, sWo1);

    // Fused pipeline
    enc_k<<<GB, 256, 0, stream>>>(feat, Benc, be, sWin, bin, xa);
    layer_k<<<GB, 256, 0, stream>>>(xa, eidx, offs, deg, sWstk, rbias, xb);
    layer_k<<<GB, 256, 0, stream>>>(xb, eidx, offs, deg, sWstk, rbias, xa);
    head_k<<<GB, 256, 0, stream>>>(xa, sWo1, bo1, Wo2, bo2, (float*)d_out);
}